// Round 1
// baseline (184600.012 us; speedup 1.0000x reference)
//
#include <hip/hip_runtime.h>
#include <math.h>

#define TSEQ 512
#define NB   128
#define HID  1024
#define VOC  256

__device__ __forceinline__ float sigmoidf_(float x) { return 1.0f / (1.0f + expf(-x)); }

// One LSTM step for one layer.
// Gate blocks (blockIdx < n_gate): each owns 4 h-columns x 4 gates (16 GEMM cols),
//   computes pre-activations over K (=1024 for layer0, 1024+256 for layer1 where the
//   extra K comes from p0_t read out of `seq`), then does the c/h update locally.
// P blocks (blockIdx >= n_gate): each owns 16 vocab cols of p_{t-1} = h_{t-1} @ Wph + bp,
//   written to seq[t-1]. (t==0: nothing to do; t==TSEQ: p-only launch.)
template<int LAYER>
__global__ __launch_bounds__(256)
void lstm_step_kernel(
    const int*   __restrict__ xtok,   // [B, T] tokens
    const float* __restrict__ Wgx, const float* __restrict__ Wgh,
    const float* __restrict__ Wix, const float* __restrict__ Wih,
    const float* __restrict__ Wfx, const float* __restrict__ Wfh,
    const float* __restrict__ Wox, const float* __restrict__ Woh,
    const float* __restrict__ Wph,
    const float* __restrict__ bg,  const float* __restrict__ bi,
    const float* __restrict__ bf_, const float* __restrict__ bo,
    const float* __restrict__ bp,
    const float* __restrict__ h_prev,  // [B, H]
    float*       __restrict__ h_cur,   // [B, H]
    float*       __restrict__ c_state, // [B, H]
    float*       __restrict__ seq,     // d_out: [T, B, V], used in-place across layers
    int t, int n_gate)
{
    __shared__ float smh[32][130];   // A-tile chunk, [kk][b], padded
    __shared__ float sme[128][20];   // gate-preact exchange, [row][gate*4+hc]
    const int tid = threadIdx.x;

    if ((int)blockIdx.x < n_gate) {
        // ---------------- gate block ----------------
        const int jb   = blockIdx.x * 4;   // h-col base (4 cols)
        const int gate = tid & 3;          // 0:g 1:i 2:f 3:o
        const int rg   = tid >> 2;         // 0..63 -> rows {2rg, 2rg+1}
        const float* Wh = (gate == 0) ? Wgh : (gate == 1) ? Wih : (gate == 2) ? Wfh : Woh;
        const float* Wx = (gate == 0) ? Wgx : (gate == 1) ? Wix : (gate == 2) ? Wfx : Wox;
        const float* bb = (gate == 0) ? bg  : (gate == 1) ? bi  : (gate == 2) ? bf_ : bo;

        float a0x = 0.f, a0y = 0.f, a0z = 0.f, a0w = 0.f;
        float a1x = 0.f, a1y = 0.f, a1z = 0.f, a1w = 0.f;

        const int KTOT = (LAYER == 0) ? HID : (HID + VOC);
        for (int kc = 0; kc < KTOT; kc += 32) {
            __syncthreads();
            {   // stage A chunk: [32 kk][128 b]
                const int u  = tid & 7;      // k-quad within chunk
                const int b0 = tid >> 3;     // 0..31
                #pragma unroll
                for (int rep = 0; rep < 4; rep++) {
                    const int b = b0 + 32 * rep;
                    const float* src = (kc < HID)
                        ? (h_prev + b * HID + kc)
                        : (seq + ((size_t)t * NB + b) * VOC + (kc - HID));
                    const float4 v = *(const float4*)(src + 4 * u);
                    smh[4 * u + 0][b] = v.x;
                    smh[4 * u + 1][b] = v.y;
                    smh[4 * u + 2][b] = v.z;
                    smh[4 * u + 3][b] = v.w;
                }
            }
            __syncthreads();
            const float* wbase = (kc < HID)
                ? (Wh + (size_t)kc * HID + jb)
                : (Wx + (size_t)(kc - HID) * HID + jb);
            #pragma unroll
            for (int kk = 0; kk < 32; kk++) {
                const float4 w  = *(const float4*)(wbase + (size_t)kk * HID);
                const float2 hv = *(const float2*)&smh[kk][rg * 2];
                a0x = fmaf(w.x, hv.x, a0x); a0y = fmaf(w.y, hv.x, a0y);
                a0z = fmaf(w.z, hv.x, a0z); a0w = fmaf(w.w, hv.x, a0w);
                a1x = fmaf(w.x, hv.y, a1x); a1y = fmaf(w.y, hv.y, a1y);
                a1z = fmaf(w.z, hv.y, a1z); a1w = fmaf(w.w, hv.y, a1w);
            }
        }

        // bias + (layer0) one-hot gather x-contrib
        const float4 bv = *(const float4*)(bb + jb);
        if (LAYER == 0) {
            const int tok0 = xtok[(rg * 2 + 0) * TSEQ + t];
            const int tok1 = xtok[(rg * 2 + 1) * TSEQ + t];
            const float4 x0 = *(const float4*)(Wx + (size_t)tok0 * HID + jb);
            const float4 x1 = *(const float4*)(Wx + (size_t)tok1 * HID + jb);
            a0x += x0.x; a0y += x0.y; a0z += x0.z; a0w += x0.w;
            a1x += x1.x; a1y += x1.y; a1z += x1.z; a1w += x1.w;
        }
        a0x += bv.x; a0y += bv.y; a0z += bv.z; a0w += bv.w;
        a1x += bv.x; a1y += bv.y; a1z += bv.z; a1w += bv.w;

        // exchange pre-activations so each (row, hcol) sees all 4 gates
        *(float4*)&sme[rg * 2 + 0][gate * 4] = make_float4(a0x, a0y, a0z, a0w);
        *(float4*)&sme[rg * 2 + 1][gate * 4] = make_float4(a1x, a1y, a1z, a1w);
        __syncthreads();

        #pragma unroll
        for (int e = 0; e < 2; e++) {
            const int el  = e * 256 + tid;    // 0..511
            const int row = el >> 2;
            const int hc  = el & 3;
            const float gg = tanhf(sme[row][0 + hc]);
            const float ii = sigmoidf_(sme[row][4 + hc]);
            const float ff = sigmoidf_(sme[row][8 + hc]);
            const float oo = sigmoidf_(sme[row][12 + hc]);
            const int j = jb + hc;
            const float co = c_state[row * HID + j];
            const float cn = fmaf(gg, ii, co * ff);
            const float hn = tanhf(cn) * oo;
            c_state[row * HID + j] = cn;
            h_cur[row * HID + j]   = hn;
        }
    } else {
        // ---------------- p block: p_{t-1} = h_{t-1} @ Wph + bp ----------------
        if (t == 0) return;
        const int pb  = blockIdx.x - n_gate;
        const int jbp = pb * 16;
        const int rg  = tid >> 2;   // rows {2rg, 2rg+1}
        const int cg  = tid & 3;    // 4 cols each

        float a0x = 0.f, a0y = 0.f, a0z = 0.f, a0w = 0.f;
        float a1x = 0.f, a1y = 0.f, a1z = 0.f, a1w = 0.f;

        for (int kc = 0; kc < HID; kc += 32) {
            __syncthreads();
            {
                const int u  = tid & 7;
                const int b0 = tid >> 3;
                #pragma unroll
                for (int rep = 0; rep < 4; rep++) {
                    const int b = b0 + 32 * rep;
                    const float4 v = *(const float4*)(h_prev + b * HID + kc + 4 * u);
                    smh[4 * u + 0][b] = v.x;
                    smh[4 * u + 1][b] = v.y;
                    smh[4 * u + 2][b] = v.z;
                    smh[4 * u + 3][b] = v.w;
                }
            }
            __syncthreads();
            const float* wbase = Wph + (size_t)kc * VOC + jbp + cg * 4;
            #pragma unroll
            for (int kk = 0; kk < 32; kk++) {
                const float4 w  = *(const float4*)(wbase + (size_t)kk * VOC);
                const float2 hv = *(const float2*)&smh[kk][rg * 2];
                a0x = fmaf(w.x, hv.x, a0x); a0y = fmaf(w.y, hv.x, a0y);
                a0z = fmaf(w.z, hv.x, a0z); a0w = fmaf(w.w, hv.x, a0w);
                a1x = fmaf(w.x, hv.y, a1x); a1y = fmaf(w.y, hv.y, a1y);
                a1z = fmaf(w.z, hv.y, a1z); a1w = fmaf(w.w, hv.y, a1w);
            }
        }
        const float4 bv = *(const float4*)(bp + jbp + cg * 4);
        const int r0 = rg * 2, r1 = rg * 2 + 1;
        float4 o0 = make_float4(a0x + bv.x, a0y + bv.y, a0z + bv.z, a0w + bv.w);
        float4 o1 = make_float4(a1x + bv.x, a1y + bv.y, a1z + bv.z, a1w + bv.w);
        *(float4*)(seq + ((size_t)(t - 1) * NB + r0) * VOC + jbp + cg * 4) = o0;
        *(float4*)(seq + ((size_t)(t - 1) * NB + r1) * VOC + jbp + cg * 4) = o1;
    }
}

extern "C" void kernel_launch(void* const* d_in, const int* in_sizes, int n_in,
                              void* d_out, int out_size, void* d_ws, size_t ws_size,
                              hipStream_t stream)
{
    const int*   x   = (const int*)  d_in[0];
    const float* Wgx = (const float*)d_in[1];
    const float* Wgh = (const float*)d_in[2];
    const float* Wix = (const float*)d_in[3];
    const float* Wih = (const float*)d_in[4];
    const float* Wfx = (const float*)d_in[5];
    const float* Wfh = (const float*)d_in[6];
    const float* Wox = (const float*)d_in[7];
    const float* Woh = (const float*)d_in[8];
    const float* Wph = (const float*)d_in[9];
    const float* bg  = (const float*)d_in[10];
    const float* bi  = (const float*)d_in[11];
    const float* bf  = (const float*)d_in[12];
    const float* bo  = (const float*)d_in[13];
    const float* bp  = (const float*)d_in[14];

    float* seq = (float*)d_out;
    float* hA  = (float*)d_ws;           // [B,H]
    float* hB  = hA + NB * HID;          // [B,H]
    float* cS  = hB + NB * HID;          // [B,H]

    for (int layer = 0; layer < 2; layer++) {
        hipMemsetAsync(hA, 0, NB * HID * sizeof(float), stream);
        hipMemsetAsync(cS, 0, NB * HID * sizeof(float), stream);

        const float* wgx = Wgx + (size_t)layer * VOC * HID;
        const float* wgh = Wgh + (size_t)layer * HID * HID;
        const float* wix = Wix + (size_t)layer * VOC * HID;
        const float* wih = Wih + (size_t)layer * HID * HID;
        const float* wfx = Wfx + (size_t)layer * VOC * HID;
        const float* wfh = Wfh + (size_t)layer * HID * HID;
        const float* wox = Wox + (size_t)layer * VOC * HID;
        const float* woh = Woh + (size_t)layer * HID * HID;
        const float* wph = Wph + (size_t)layer * HID * VOC;
        const float* pbg = bg + (size_t)layer * HID;
        const float* pbi = bi + (size_t)layer * HID;
        const float* pbf = bf + (size_t)layer * HID;
        const float* pbo = bo + (size_t)layer * HID;
        const float* pbp = bp + (size_t)layer * VOC;

        for (int t = 0; t <= TSEQ; t++) {
            const float* hp = (t & 1) ? hB : hA;
            float*       hc = (t & 1) ? hA : hB;
            const int ng = (t == TSEQ) ? 0 : 256;   // gate blocks
            const int np = (t == 0)    ? 0 : 16;    // p blocks
            dim3 grid(ng + np), blk(256);
            if (layer == 0) {
                hipLaunchKernelGGL((lstm_step_kernel<0>), grid, blk, 0, stream,
                    x, wgx, wgh, wix, wih, wfx, wfh, wox, woh, wph,
                    pbg, pbi, pbf, pbo, pbp,
                    hp, hc, cS, seq, t, ng);
            } else {
                hipLaunchKernelGGL((lstm_step_kernel<1>), grid, blk, 0, stream,
                    x, wgx, wgh, wix, wih, wfx, wfh, wox, woh, wph,
                    pbg, pbi, pbf, pbo, pbp,
                    hp, hc, cS, seq, t, ng);
            }
        }
    }
}

// Round 2
// 129579.553 us; speedup vs baseline: 1.4246x; 1.4246x over previous
//
#include <hip/hip_runtime.h>
#include <hip/hip_cooperative_groups.h>
#include <math.h>

namespace cg = cooperative_groups;

#define TT   512
#define BB   128
#define HH   1024
#define VV   256
#define KC   64
#define NTHR 512
#define NBLK 256

__device__ __forceinline__ float sigf(float x) { return 1.0f / (1.0f + expf(-x)); }

// Persistent 2-layer LSTM. 256 blocks (1/CU), 512 threads.
// Block owns gate-cols [4 hcols x 4 gates] and one p-column (pcol = blockIdx).
// h stored globally TRANSPOSED hT[k][b] (fp32, ping-pong in ws).
// Layer 0 writes p0 transposed [t][v][b] into seq (d_out) as scratch;
// layer 1 reads it as K-extension and overwrites slice t-1 with p1 in [t][b][v].
__global__ __launch_bounds__(NTHR, 1)
void lstm_persist(
    const int*   __restrict__ x,
    const float* __restrict__ Wgx, const float* __restrict__ Wgh,
    const float* __restrict__ Wix, const float* __restrict__ Wih,
    const float* __restrict__ Wfx, const float* __restrict__ Wfh,
    const float* __restrict__ Wox, const float* __restrict__ Woh,
    const float* __restrict__ Wph,
    const float* __restrict__ bg,  const float* __restrict__ bi,
    const float* __restrict__ bf_, const float* __restrict__ bo,
    const float* __restrict__ bp,
    float* __restrict__ seq, float* __restrict__ hTA,
    float* __restrict__ hTB, int* __restrict__ xT)
{
  __shared__ float w_lds[(HH + VV) * 16];   // [k][gate*4+hc]  80 KB
  __shared__ float hbuf[2][KC * BB];        // [k][b] chunks   64 KB (hbuf[0] reused as gate-exchange)
  __shared__ float p_exch[16 * BB];         //                  8 KB
  __shared__ float wph_lds[HH];             // p column         4 KB
  __shared__ float bias_lds[16];

  cg::grid_group grid = cg::this_grid();
  const int tid   = threadIdx.x;
  const int bid   = blockIdx.x;
  // GEMM mapping: thread = (ks, g, rq): rows 4rq..4rq+3, cols g*4..g*4+3, K-quarter ks
  const int ks    = tid >> 7;
  const int g     = (tid >> 5) & 3;
  const int rq    = tid & 31;
  // update mapping: thread = (u_hc, u_row)
  const int u_hc  = tid >> 7;
  const int u_row = tid & 127;
  const int jb    = bid * 4;     // hcol base
  const int pcol  = bid;         // p column
  // staging mapping
  const int sk    = tid >> 5;
  const int sb    = (tid & 31) * 4;

  // transpose x[B][T] -> xT[t][b] (once)
  for (int i = bid * NTHR + tid; i < BB * TT; i += NBLK * NTHR) {
    const int b = i >> 9, t = i & (TT - 1);
    xT[t * BB + b] = x[i];
  }

  for (int layer = 0; layer < 2; layer++) {
    const float* Whs[4] = { Wgh + (size_t)layer*HH*HH, Wih + (size_t)layer*HH*HH,
                            Wfh + (size_t)layer*HH*HH, Woh + (size_t)layer*HH*HH };
    const float* Wxs[4] = { Wgx + (size_t)layer*VV*HH, Wix + (size_t)layer*VV*HH,
                            Wfx + (size_t)layer*VV*HH, Wox + (size_t)layer*VV*HH };
    const float* bbs[4] = { bg + layer*HH, bi + layer*HH, bf_ + layer*HH, bo + layer*HH };
    const float* Wph_l  = Wph + (size_t)layer*HH*VV;
    const float* bp_l   = bp + layer*VV;
    const int KTOT = layer ? (HH + VV) : HH;
    const int NCH  = KTOT / KC;

    // stage this layer's weight slice into LDS (amortized over 512 steps)
    for (int k = tid; k < KTOT; k += NTHR) {
      #pragma unroll
      for (int gg = 0; gg < 4; gg++) {
        const float* sm = (k < HH) ? (Whs[gg] + (size_t)k * HH + jb)
                                   : (Wxs[gg] + (size_t)(k - HH) * HH + jb);
        *(float4*)&w_lds[k * 16 + gg * 4] = *(const float4*)sm;
      }
    }
    for (int k = tid; k < HH; k += NTHR) wph_lds[k] = Wph_l[(size_t)k * VV + pcol];
    if (tid < 16) bias_lds[tid] = bbs[tid >> 2][jb + (tid & 3)];
    float c_reg = 0.0f;
    grid.sync();

    for (int t = 0; t <= TT; t++) {
      const float* hT_prev = (t & 1) ? hTB : hTA;
      float*       hT_cur  = (t & 1) ? hTA : hTB;
      const bool gates_on = (t < TT);
      const bool p_on     = (t > 0);
      const int  cstart   = (t == 0) ? 16 : 0;   // t=0: h==0 -> only K-ext chunks (L1); none for L0
      const int  cend     = gates_on ? NCH : 16; // epilogue: only k<1024 chunks (for p)
      const bool ran_gemm = (cstart < cend);

      float4 ac0 = {0,0,0,0}, ac1 = {0,0,0,0}, ac2 = {0,0,0,0}, ac3 = {0,0,0,0};
      float4 pa  = {0,0,0,0};

      if (ran_gemm) {  // pre-stage first chunk
        const int kc0 = cstart * KC;
        const float* sp = (kc0 < HH) ? (hT_prev + (size_t)kc0 * BB)
                                     : (seq + (size_t)t * BB * VV + (size_t)(kc0 - HH) * BB);
        float* db = hbuf[cstart & 1];
        #pragma unroll
        for (int rep = 0; rep < 4; rep++) {
          const int k2 = sk + 16 * rep;
          *(float4*)&db[k2 * BB + sb] = *(const float4*)&sp[(size_t)k2 * BB + sb];
        }
      }
      __syncthreads();

      for (int c = cstart; c < cend; c++) {
        float4 nx0, nx1, nx2, nx3;
        const bool hn = (c + 1 < cend);
        if (hn) {  // issue next-chunk loads early; land under compute
          const int kc1 = (c + 1) * KC;
          const float* sp = (kc1 < HH) ? (hT_prev + (size_t)kc1 * BB)
                                       : (seq + (size_t)t * BB * VV + (size_t)(kc1 - HH) * BB);
          nx0 = *(const float4*)&sp[(size_t)(sk     ) * BB + sb];
          nx1 = *(const float4*)&sp[(size_t)(sk + 16) * BB + sb];
          nx2 = *(const float4*)&sp[(size_t)(sk + 32) * BB + sb];
          nx3 = *(const float4*)&sp[(size_t)(sk + 48) * BB + sb];
        }
        const float* hb = hbuf[c & 1];
        if (gates_on) {
          const float* wp = &w_lds[(c * KC + ks * 16) * 16 + g * 4];
          const float* hp = &hb[(ks * 16) * BB + rq * 4];
          #pragma unroll
          for (int kk = 0; kk < 16; kk++) {
            const float4 h4 = *(const float4*)&hp[kk * BB];
            const float4 w4 = *(const float4*)&wp[kk * 16];
            ac0.x = fmaf(h4.x, w4.x, ac0.x); ac0.y = fmaf(h4.x, w4.y, ac0.y);
            ac0.z = fmaf(h4.x, w4.z, ac0.z); ac0.w = fmaf(h4.x, w4.w, ac0.w);
            ac1.x = fmaf(h4.y, w4.x, ac1.x); ac1.y = fmaf(h4.y, w4.y, ac1.y);
            ac1.z = fmaf(h4.y, w4.z, ac1.z); ac1.w = fmaf(h4.y, w4.w, ac1.w);
            ac2.x = fmaf(h4.z, w4.x, ac2.x); ac2.y = fmaf(h4.z, w4.y, ac2.y);
            ac2.z = fmaf(h4.z, w4.z, ac2.z); ac2.w = fmaf(h4.z, w4.w, ac2.w);
            ac3.x = fmaf(h4.w, w4.x, ac3.x); ac3.y = fmaf(h4.w, w4.y, ac3.y);
            ac3.z = fmaf(h4.w, w4.z, ac3.z); ac3.w = fmaf(h4.w, w4.w, ac3.w);
          }
        }
        if (p_on && c < 16) {  // p-fold: 16 (g,ks)-groups x 4 k cover the 64-k chunk
          const int kb = (g * 4 + ks) * 4;
          const float* hp2 = &hb[kb * BB + rq * 4];
          const float* wq  = &wph_lds[c * KC + kb];
          #pragma unroll
          for (int j = 0; j < 4; j++) {
            const float4 h4 = *(const float4*)&hp2[j * BB];
            const float  wv = wq[j];
            pa.x = fmaf(h4.x, wv, pa.x); pa.y = fmaf(h4.y, wv, pa.y);
            pa.z = fmaf(h4.z, wv, pa.z); pa.w = fmaf(h4.w, wv, pa.w);
          }
        }
        if (hn) {  // write next chunk to the other buffer
          float* db = hbuf[(c + 1) & 1];
          *(float4*)&db[(sk     ) * BB + sb] = nx0;
          *(float4*)&db[(sk + 16) * BB + sb] = nx1;
          *(float4*)&db[(sk + 32) * BB + sb] = nx2;
          *(float4*)&db[(sk + 48) * BB + sb] = nx3;
        }
        __syncthreads();
      }

      // exchange partials
      if (gates_on && ran_gemm) {
        float* gex = &hbuf[0][0];  // 8192 floats = [ksg 16][hc 4][row 128]
        const int kg = ks * 4 + g;
        *(float4*)&gex[((kg * 4) + 0) * BB + rq * 4] = make_float4(ac0.x, ac1.x, ac2.x, ac3.x);
        *(float4*)&gex[((kg * 4) + 1) * BB + rq * 4] = make_float4(ac0.y, ac1.y, ac2.y, ac3.y);
        *(float4*)&gex[((kg * 4) + 2) * BB + rq * 4] = make_float4(ac0.z, ac1.z, ac2.z, ac3.z);
        *(float4*)&gex[((kg * 4) + 3) * BB + rq * 4] = make_float4(ac0.w, ac1.w, ac2.w, ac3.w);
      }
      if (p_on) {
        *(float4*)&p_exch[(ks * 4 + g) * BB + rq * 4] = pa;
      }
      __syncthreads();

      // update phase: thread = (u_row, u_hc); c lives in a register
      if (gates_on) {
        float pre0 = bias_lds[ 0 + u_hc], pre1 = bias_lds[ 4 + u_hc];
        float pre2 = bias_lds[ 8 + u_hc], pre3 = bias_lds[12 + u_hc];
        if (ran_gemm) {
          const float* gex = &hbuf[0][0];
          #pragma unroll
          for (int k2 = 0; k2 < 4; k2++) {
            pre0 += gex[((k2 * 4 + 0) * 4 + u_hc) * BB + u_row];
            pre1 += gex[((k2 * 4 + 1) * 4 + u_hc) * BB + u_row];
            pre2 += gex[((k2 * 4 + 2) * 4 + u_hc) * BB + u_row];
            pre3 += gex[((k2 * 4 + 3) * 4 + u_hc) * BB + u_row];
          }
        }
        if (layer == 0) {  // one-hot x-contribution: row gather
          const int tok = xT[t * BB + u_row];
          const size_t off = (size_t)tok * HH + jb + u_hc;
          pre0 += Wxs[0][off]; pre1 += Wxs[1][off];
          pre2 += Wxs[2][off]; pre3 += Wxs[3][off];
        }
        const float G = tanhf(pre0);
        const float I = sigf(pre1);
        const float F = sigf(pre2);
        const float O = sigf(pre3);
        c_reg = fmaf(G, I, c_reg * F);
        const float hv = tanhf(c_reg) * O;
        hT_cur[(size_t)(jb + u_hc) * BB + u_row] = hv;  // transposed, coalesced
      }
      if (p_on && tid < BB) {  // reduce p partials, write p_{t-1}
        float s = bp_l[pcol];
        #pragma unroll
        for (int j = 0; j < 16; j++) s += p_exch[j * BB + tid];
        if (layer == 0) seq[(size_t)(t - 1) * BB * VV + (size_t)pcol * BB + tid] = s; // [t][v][b]
        else            seq[(size_t)(t - 1) * BB * VV + (size_t)tid * VV + pcol] = s; // [t][b][v]
      }
      __threadfence();   // release: flush h/p writes toward device scope
      grid.sync();
      __threadfence();   // acquire: invalidate stale L1/L2 before next step's reads
    }
  }
}

extern "C" void kernel_launch(void* const* d_in, const int* in_sizes, int n_in,
                              void* d_out, int out_size, void* d_ws, size_t ws_size,
                              hipStream_t stream)
{
  const int*   x   = (const int*)  d_in[0];
  const float* Wgx = (const float*)d_in[1];
  const float* Wgh = (const float*)d_in[2];
  const float* Wix = (const float*)d_in[3];
  const float* Wih = (const float*)d_in[4];
  const float* Wfx = (const float*)d_in[5];
  const float* Wfh = (const float*)d_in[6];
  const float* Wox = (const float*)d_in[7];
  const float* Woh = (const float*)d_in[8];
  const float* Wph = (const float*)d_in[9];
  const float* bg  = (const float*)d_in[10];
  const float* bi  = (const float*)d_in[11];
  const float* bf  = (const float*)d_in[12];
  const float* bo  = (const float*)d_in[13];
  const float* bp  = (const float*)d_in[14];

  float* seq = (float*)d_out;
  int*   xT  = (int*)d_ws;                                  // 256 KB
  float* hTA = (float*)((char*)d_ws + BB * TT * sizeof(int)); // 512 KB
  float* hTB = hTA + (size_t)BB * HH;                         // 512 KB

  void* args[] = { (void*)&x,
                   (void*)&Wgx, (void*)&Wgh, (void*)&Wix, (void*)&Wih,
                   (void*)&Wfx, (void*)&Wfh, (void*)&Wox, (void*)&Woh,
                   (void*)&Wph,
                   (void*)&bg, (void*)&bi, (void*)&bf, (void*)&bo, (void*)&bp,
                   (void*)&seq, (void*)&hTA, (void*)&hTB, (void*)&xT };

  hipLaunchCooperativeKernel((const void*)lstm_persist, dim3(NBLK), dim3(NTHR),
                             args, 0, stream);
}

// Round 3
// 46448.355 us; speedup vs baseline: 3.9743x; 2.7898x over previous
//
#include <hip/hip_runtime.h>
#include <math.h>

#define TT   512
#define BB   128
#define HH   1024
#define VV   256
#define KC   64
#define NTHR 512
#define NBLK 256

__device__ __forceinline__ float sigf(float x) { return 1.0f / (1.0f + expf(-x)); }

// Device-coherent (agent-scope, cache-bypassing) accessors for cross-block data.
__device__ __forceinline__ void st_dev(float* p, float v) {
  __hip_atomic_store(p, v, __ATOMIC_RELAXED, __HIP_MEMORY_SCOPE_AGENT);
}
__device__ __forceinline__ float ld_dev(const float* p) {
  return __hip_atomic_load(p, __ATOMIC_RELAXED, __HIP_MEMORY_SCOPE_AGENT);
}
__device__ __forceinline__ void st_dev_i(int* p, int v) {
  __hip_atomic_store(p, v, __ATOMIC_RELAXED, __HIP_MEMORY_SCOPE_AGENT);
}

// Lightweight grid barrier: monotonic counter, no fences.
// The leading __syncthreads drains every wave's vmcnt (sc-stores reach the
// device-coherent point), so arrival implies visibility of this block's
// cross-block stores. Cross-block data is accessed with sc-bypass ops, so no
// L2 writeback/invalidate is needed on either side.
__device__ __forceinline__ void gbar(unsigned* cnt, unsigned target) {
  __syncthreads();
  if (threadIdx.x == 0) {
    __hip_atomic_fetch_add(cnt, 1u, __ATOMIC_RELAXED, __HIP_MEMORY_SCOPE_AGENT);
    while (__hip_atomic_load(cnt, __ATOMIC_RELAXED, __HIP_MEMORY_SCOPE_AGENT) < target)
      __builtin_amdgcn_s_sleep(2);
  }
  __syncthreads();
  asm volatile("" ::: "memory");
}

// Persistent 2-layer LSTM. 256 blocks (1/CU), 512 threads.
// Block owns gate-cols [4 hcols x 4 gates] and one p-column (pcol = blockIdx).
// h stored globally TRANSPOSED hT[k][b] (fp32, ping-pong in ws), sc-coherent.
// Layer 0 writes p0 transposed [t][v][b] into seq (d_out) as scratch;
// layer 1 reads it as K-extension and overwrites slice t-1 with p1 in [t][b][v].
__global__ __launch_bounds__(NTHR, 1)
void lstm_persist(
    const int*   __restrict__ x,
    const float* __restrict__ Wgx, const float* __restrict__ Wgh,
    const float* __restrict__ Wix, const float* __restrict__ Wih,
    const float* __restrict__ Wfx, const float* __restrict__ Wfh,
    const float* __restrict__ Wox, const float* __restrict__ Woh,
    const float* __restrict__ Wph,
    const float* __restrict__ bg,  const float* __restrict__ bi,
    const float* __restrict__ bf_, const float* __restrict__ bo,
    const float* __restrict__ bp,
    float* __restrict__ seq, float* __restrict__ hTA,
    float* __restrict__ hTB, int* __restrict__ xT,
    unsigned* __restrict__ barcnt)
{
  __shared__ float w_lds[(HH + VV) * 16];   // [k][gate*4+hc]  80 KB
  __shared__ float hbuf[2][KC * BB];        // [k][b] chunks   64 KB (hbuf[0] reused as gate-exchange)
  __shared__ float p_exch[16 * BB];         //                  8 KB
  __shared__ float wph_lds[HH];             // p column         4 KB
  __shared__ float bias_lds[16];

  const int tid   = threadIdx.x;
  const int bid   = blockIdx.x;
  // GEMM mapping: thread = (ks, g, rq): rows 4rq..4rq+3, cols g*4..g*4+3, K-quarter ks
  const int ks    = tid >> 7;
  const int g     = (tid >> 5) & 3;
  const int rq    = tid & 31;
  // update mapping: thread = (u_hc, u_row)
  const int u_hc  = tid >> 7;
  const int u_row = tid & 127;
  const int jb    = bid * 4;     // hcol base
  const int pcol  = bid;         // p column
  // staging mapping
  const int sk    = tid >> 5;
  const int sb    = (tid & 31) * 4;

  unsigned nbar = 0;

  // transpose x[B][T] -> xT[t][b] (once); sc-stores so later cached reads are fresh
  for (int i = bid * NTHR + tid; i < BB * TT; i += NBLK * NTHR) {
    const int b = i >> 9, t = i & (TT - 1);
    st_dev_i(&xT[t * BB + b], x[i]);
  }

  for (int layer = 0; layer < 2; layer++) {
    const float* Whs[4] = { Wgh + (size_t)layer*HH*HH, Wih + (size_t)layer*HH*HH,
                            Wfh + (size_t)layer*HH*HH, Woh + (size_t)layer*HH*HH };
    const float* Wxs[4] = { Wgx + (size_t)layer*VV*HH, Wix + (size_t)layer*VV*HH,
                            Wfx + (size_t)layer*VV*HH, Wox + (size_t)layer*VV*HH };
    const float* bbs[4] = { bg + layer*HH, bi + layer*HH, bf_ + layer*HH, bo + layer*HH };
    const float* Wph_l  = Wph + (size_t)layer*HH*VV;
    const float* bp_l   = bp + layer*VV;
    const int KTOT = layer ? (HH + VV) : HH;
    const int NCH  = KTOT / KC;

    // stage this layer's weight slice into LDS (amortized over 512 steps)
    for (int k = tid; k < KTOT; k += NTHR) {
      #pragma unroll
      for (int gg = 0; gg < 4; gg++) {
        const float* sm = (k < HH) ? (Whs[gg] + (size_t)k * HH + jb)
                                   : (Wxs[gg] + (size_t)(k - HH) * HH + jb);
        *(float4*)&w_lds[k * 16 + gg * 4] = *(const float4*)sm;
      }
    }
    for (int k = tid; k < HH; k += NTHR) wph_lds[k] = Wph_l[(size_t)k * VV + pcol];
    if (tid < 16) bias_lds[tid] = bbs[tid >> 2][jb + (tid & 3)];
    float c_reg = 0.0f;
    gbar(barcnt, (++nbar) * NBLK);

    for (int t = 0; t <= TT; t++) {
      const float* hT_prev = (t & 1) ? hTB : hTA;
      float*       hT_cur  = (t & 1) ? hTA : hTB;
      const bool gates_on = (t < TT);
      const bool p_on     = (t > 0);
      const int  cstart   = (t == 0) ? 16 : 0;   // t=0: h==0 -> only K-ext chunks (L1); none for L0
      const int  cend     = gates_on ? NCH : 16; // epilogue: only k<1024 chunks (for p)
      const bool ran_gemm = (cstart < cend);

      float4 ac0 = {0,0,0,0}, ac1 = {0,0,0,0}, ac2 = {0,0,0,0}, ac3 = {0,0,0,0};
      float4 pa  = {0,0,0,0};

      if (ran_gemm) {  // pre-stage first chunk (sc-coherent scalar loads)
        const int kc0 = cstart * KC;
        const float* sp = (kc0 < HH) ? (hT_prev + (size_t)kc0 * BB)
                                     : (seq + (size_t)t * BB * VV + (size_t)(kc0 - HH) * BB);
        float* db = hbuf[cstart & 1];
        #pragma unroll
        for (int rep = 0; rep < 4; rep++) {
          const int k2 = sk + 16 * rep;
          const float* q = sp + (size_t)k2 * BB + sb;
          float4 v;
          v.x = ld_dev(q + 0); v.y = ld_dev(q + 1);
          v.z = ld_dev(q + 2); v.w = ld_dev(q + 3);
          *(float4*)&db[k2 * BB + sb] = v;
        }
      }
      __syncthreads();

      for (int c = cstart; c < cend; c++) {
        float4 nx0, nx1, nx2, nx3;
        const bool hn = (c + 1 < cend);
        if (hn) {  // issue next-chunk loads early; land under compute
          const int kc1 = (c + 1) * KC;
          const float* sp = (kc1 < HH) ? (hT_prev + (size_t)kc1 * BB)
                                       : (seq + (size_t)t * BB * VV + (size_t)(kc1 - HH) * BB);
          const float* q0 = sp + (size_t)(sk     ) * BB + sb;
          const float* q1 = sp + (size_t)(sk + 16) * BB + sb;
          const float* q2 = sp + (size_t)(sk + 32) * BB + sb;
          const float* q3 = sp + (size_t)(sk + 48) * BB + sb;
          nx0.x = ld_dev(q0+0); nx0.y = ld_dev(q0+1); nx0.z = ld_dev(q0+2); nx0.w = ld_dev(q0+3);
          nx1.x = ld_dev(q1+0); nx1.y = ld_dev(q1+1); nx1.z = ld_dev(q1+2); nx1.w = ld_dev(q1+3);
          nx2.x = ld_dev(q2+0); nx2.y = ld_dev(q2+1); nx2.z = ld_dev(q2+2); nx2.w = ld_dev(q2+3);
          nx3.x = ld_dev(q3+0); nx3.y = ld_dev(q3+1); nx3.z = ld_dev(q3+2); nx3.w = ld_dev(q3+3);
        }
        const float* hb = hbuf[c & 1];
        if (gates_on) {
          const float* wp = &w_lds[(c * KC + ks * 16) * 16 + g * 4];
          const float* hp = &hb[(ks * 16) * BB + rq * 4];
          #pragma unroll
          for (int kk = 0; kk < 16; kk++) {
            const float4 h4 = *(const float4*)&hp[kk * BB];
            const float4 w4 = *(const float4*)&wp[kk * 16];
            ac0.x = fmaf(h4.x, w4.x, ac0.x); ac0.y = fmaf(h4.x, w4.y, ac0.y);
            ac0.z = fmaf(h4.x, w4.z, ac0.z); ac0.w = fmaf(h4.x, w4.w, ac0.w);
            ac1.x = fmaf(h4.y, w4.x, ac1.x); ac1.y = fmaf(h4.y, w4.y, ac1.y);
            ac1.z = fmaf(h4.y, w4.z, ac1.z); ac1.w = fmaf(h4.y, w4.w, ac1.w);
            ac2.x = fmaf(h4.z, w4.x, ac2.x); ac2.y = fmaf(h4.z, w4.y, ac2.y);
            ac2.z = fmaf(h4.z, w4.z, ac2.z); ac2.w = fmaf(h4.z, w4.w, ac2.w);
            ac3.x = fmaf(h4.w, w4.x, ac3.x); ac3.y = fmaf(h4.w, w4.y, ac3.y);
            ac3.z = fmaf(h4.w, w4.z, ac3.z); ac3.w = fmaf(h4.w, w4.w, ac3.w);
          }
        }
        if (p_on && c < 16) {  // p-fold: 16 (g,ks)-groups x 4 k cover the 64-k chunk
          const int kb = (g * 4 + ks) * 4;
          const float* hp2 = &hb[kb * BB + rq * 4];
          const float* wq  = &wph_lds[c * KC + kb];
          #pragma unroll
          for (int j = 0; j < 4; j++) {
            const float4 h4 = *(const float4*)&hp2[j * BB];
            const float  wv = wq[j];
            pa.x = fmaf(h4.x, wv, pa.x); pa.y = fmaf(h4.y, wv, pa.y);
            pa.z = fmaf(h4.z, wv, pa.z); pa.w = fmaf(h4.w, wv, pa.w);
          }
        }
        if (hn) {  // write next chunk to the other buffer
          float* db = hbuf[(c + 1) & 1];
          *(float4*)&db[(sk     ) * BB + sb] = nx0;
          *(float4*)&db[(sk + 16) * BB + sb] = nx1;
          *(float4*)&db[(sk + 32) * BB + sb] = nx2;
          *(float4*)&db[(sk + 48) * BB + sb] = nx3;
        }
        __syncthreads();
      }

      // exchange partials
      if (gates_on && ran_gemm) {
        float* gex = &hbuf[0][0];  // 8192 floats = [ksg 16][hc 4][row 128]
        const int kg = ks * 4 + g;
        *(float4*)&gex[((kg * 4) + 0) * BB + rq * 4] = make_float4(ac0.x, ac1.x, ac2.x, ac3.x);
        *(float4*)&gex[((kg * 4) + 1) * BB + rq * 4] = make_float4(ac0.y, ac1.y, ac2.y, ac3.y);
        *(float4*)&gex[((kg * 4) + 2) * BB + rq * 4] = make_float4(ac0.z, ac1.z, ac2.z, ac3.z);
        *(float4*)&gex[((kg * 4) + 3) * BB + rq * 4] = make_float4(ac0.w, ac1.w, ac2.w, ac3.w);
      }
      if (p_on) {
        *(float4*)&p_exch[(ks * 4 + g) * BB + rq * 4] = pa;
      }
      __syncthreads();

      // update phase: thread = (u_row, u_hc); c lives in a register
      if (gates_on) {
        float pre0 = bias_lds[ 0 + u_hc], pre1 = bias_lds[ 4 + u_hc];
        float pre2 = bias_lds[ 8 + u_hc], pre3 = bias_lds[12 + u_hc];
        if (ran_gemm) {
          const float* gex = &hbuf[0][0];
          #pragma unroll
          for (int k2 = 0; k2 < 4; k2++) {
            pre0 += gex[((k2 * 4 + 0) * 4 + u_hc) * BB + u_row];
            pre1 += gex[((k2 * 4 + 1) * 4 + u_hc) * BB + u_row];
            pre2 += gex[((k2 * 4 + 2) * 4 + u_hc) * BB + u_row];
            pre3 += gex[((k2 * 4 + 3) * 4 + u_hc) * BB + u_row];
          }
        }
        if (layer == 0) {  // one-hot x-contribution: row gather (stays L2-warm now)
          const int tok = xT[t * BB + u_row];
          const size_t off = (size_t)tok * HH + jb + u_hc;
          pre0 += Wxs[0][off]; pre1 += Wxs[1][off];
          pre2 += Wxs[2][off]; pre3 += Wxs[3][off];
        }
        const float G = tanhf(pre0);
        const float I = sigf(pre1);
        const float F = sigf(pre2);
        const float O = sigf(pre3);
        c_reg = fmaf(G, I, c_reg * F);
        const float hv = tanhf(c_reg) * O;
        st_dev(&hT_cur[(size_t)(jb + u_hc) * BB + u_row], hv);  // transposed, coalesced, sc-coherent
      }
      if (p_on && tid < BB) {  // reduce p partials, write p_{t-1}
        float s = bp_l[pcol];
        #pragma unroll
        for (int j = 0; j < 16; j++) s += p_exch[j * BB + tid];
        if (layer == 0)
          st_dev(&seq[(size_t)(t - 1) * BB * VV + (size_t)pcol * BB + tid], s); // [t][v][b], read by L1
        else
          seq[(size_t)(t - 1) * BB * VV + (size_t)tid * VV + pcol] = s;         // [t][b][v], final out (cached)
      }
      gbar(barcnt, (++nbar) * NBLK);
    }
  }
}

extern "C" void kernel_launch(void* const* d_in, const int* in_sizes, int n_in,
                              void* d_out, int out_size, void* d_ws, size_t ws_size,
                              hipStream_t stream)
{
  const int*   x   = (const int*)  d_in[0];
  const float* Wgx = (const float*)d_in[1];
  const float* Wgh = (const float*)d_in[2];
  const float* Wix = (const float*)d_in[3];
  const float* Wih = (const float*)d_in[4];
  const float* Wfx = (const float*)d_in[5];
  const float* Wfh = (const float*)d_in[6];
  const float* Wox = (const float*)d_in[7];
  const float* Woh = (const float*)d_in[8];
  const float* Wph = (const float*)d_in[9];
  const float* bg  = (const float*)d_in[10];
  const float* bi  = (const float*)d_in[11];
  const float* bf  = (const float*)d_in[12];
  const float* bo  = (const float*)d_in[13];
  const float* bp  = (const float*)d_in[14];

  float* seq = (float*)d_out;
  unsigned* barcnt = (unsigned*)d_ws;                          // 256 B
  int*   xT  = (int*)((char*)d_ws + 256);                      // 256 KB
  float* hTA = (float*)((char*)d_ws + 256 + (size_t)BB * TT * sizeof(int));
  float* hTB = hTA + (size_t)BB * HH;

  hipMemsetAsync(barcnt, 0, 256, stream);

  void* args[] = { (void*)&x,
                   (void*)&Wgx, (void*)&Wgh, (void*)&Wix, (void*)&Wih,
                   (void*)&Wfx, (void*)&Wfh, (void*)&Wox, (void*)&Woh,
                   (void*)&Wph,
                   (void*)&bg, (void*)&bi, (void*)&bf, (void*)&bo, (void*)&bp,
                   (void*)&seq, (void*)&hTA, (void*)&hTB, (void*)&xT,
                   (void*)&barcnt };

  hipLaunchCooperativeKernel((const void*)lstm_persist, dim3(NBLK), dim3(NTHR),
                             args, 0, stream);
}

// Round 4
// 13399.948 us; speedup vs baseline: 13.7762x; 3.4663x over previous
//
#include <hip/hip_runtime.h>
#include <math.h>

#define TT 512
#define BB 128
#define HH 1024
#define VV 256
#define NTHR 512
#define NBLK 256

typedef __attribute__((ext_vector_type(4))) int   i32x4;
typedef __attribute__((ext_vector_type(8))) short s16x8;
typedef __attribute__((ext_vector_type(4))) float f32x4;

__device__ __forceinline__ float sigf(float x){ return 1.0f/(1.0f+expf(-x)); }
__device__ __forceinline__ unsigned short bf16hi(float f){
  unsigned u = __float_as_uint(f);
  unsigned r = u + 0x7FFFu + ((u>>16)&1u);
  return (unsigned short)(r>>16);
}
__device__ __forceinline__ float bf16dec(unsigned short h){ return __uint_as_float(((unsigned)h)<<16); }
__device__ __forceinline__ void st16(unsigned short* p, unsigned short v){
  __hip_atomic_store(p, v, __ATOMIC_RELAXED, __HIP_MEMORY_SCOPE_AGENT);
}

// device-coherent 16B load (bypasses possibly-stale per-XCD L2)
#define SCLOAD(dst, ptr) asm volatile("global_load_dwordx4 %0, %1, off sc1" : "=v"(dst) : "v"(ptr))
// waits tied to the loaded regs via dataflow so MFMA can't be hoisted above them
#define WAIT0_2(a,b) asm volatile("s_waitcnt vmcnt(0)" : "+v"(a),"+v"(b))
#define WAIT0_4(a,b,c,d) asm volatile("s_waitcnt vmcnt(0)" : "+v"(a),"+v"(b),"+v"(c),"+v"(d))
#define WAIT0_8(a,b,c,d,e,f,g,h) asm volatile("s_waitcnt vmcnt(0)" : "+v"(a),"+v"(b),"+v"(c),"+v"(d),"+v"(e),"+v"(f),"+v"(g),"+v"(h))

// contention-free grid barrier: per-block flags, 256-lane parallel poll
__device__ __forceinline__ void gbar(unsigned* flags, unsigned rnd, int tid, int bid){
  __syncthreads();   // drains vmcnt(0): all this block's sc-stores are device-visible
  if (tid == 0) __hip_atomic_store(&flags[bid], rnd, __ATOMIC_RELAXED, __HIP_MEMORY_SCOPE_AGENT);
  if (tid < NBLK) {
    int spins = 0;
    while (__hip_atomic_load(&flags[tid], __ATOMIC_RELAXED, __HIP_MEMORY_SCOPE_AGENT) < rnd) {
      __builtin_amdgcn_s_sleep(1);
      if (++spins > (1<<28)) break;   // deadlock insurance
    }
  }
  __syncthreads();
}

// one 3-pass (hi/lo x hi/lo, lo*lo dropped) K=32 MFMA step against staged w-frags
#define GBODY(AH, AL, KC) { \
  s16x8 bh_ = *(const s16x8*)&wlds[(((KC)*2+0)*64+lane)*8]; \
  s16x8 bl_ = *(const s16x8*)&wlds[(((KC)*2+1)*64+lane)*8]; \
  s16x8 ah_ = __builtin_bit_cast(s16x8, AH); \
  s16x8 al_ = __builtin_bit_cast(s16x8, AL); \
  acc = __builtin_amdgcn_mfma_f32_16x16x32_bf16(ah_, bh_, acc, 0,0,0); \
  acc = __builtin_amdgcn_mfma_f32_16x16x32_bf16(ah_, bl_, acc, 0,0,0); \
  acc = __builtin_amdgcn_mfma_f32_16x16x32_bf16(al_, bh_, acc, 0,0,0); \
}

// hF layout: [strip s 0..7][kc 0..31][plane hi/lo][lane 0..63][j 0..7] bf16
// A-frag for (s,kc,plane) = one coalesced 16B/lane load at lane*16.
// element (b,k): s=b>>4, kc=k>>5, lane=(b&15)+16*((k>>3)&3), j=k&7.

__global__ __launch_bounds__(NTHR, 1)
void lstm_mfma(
    const int*   __restrict__ x,
    const float* __restrict__ Wgx, const float* __restrict__ Wgh,
    const float* __restrict__ Wix, const float* __restrict__ Wih,
    const float* __restrict__ Wfx, const float* __restrict__ Wfh,
    const float* __restrict__ Wox, const float* __restrict__ Woh,
    const float* __restrict__ Wph,
    const float* __restrict__ bg,  const float* __restrict__ bi,
    const float* __restrict__ bf_, const float* __restrict__ bo,
    const float* __restrict__ bp,
    float* __restrict__ seq, char* __restrict__ hFA, char* __restrict__ hFB,
    float* __restrict__ gpart, int* __restrict__ xT, unsigned* __restrict__ flags)
{
  __shared__ unsigned short wlds[40*2*64*8];   // gate B-frags hi/lo   80 KB
  __shared__ unsigned short wplds[16*2*64*8];  // wph B-frags          32 KB
  __shared__ float zex[BB*16];                 // gate D exchange       8 KB
  __shared__ float pex[8*256];                 // p D partials          8 KB

  const int tid = threadIdx.x, bid = blockIdx.x;
  const int wv   = tid>>6;        // wave id = gate row-strip
  const int lane = tid&63;
  const int jb   = bid*4;         // hcol base (block owns 16 cols = 4 gates x 4 hcols)
  const int p_cg = bid & 15;      // p-slice: col-group (pcols p_cg*16..+15)
  const int p_s  = (bid>>4)&7;    //          row strip
  const int p_kh = bid>>7;        //          k-half (0/1)
  const int u_hc = tid>>7, u_b = tid&127;   // update mapping: (hcol, row)

  unsigned roundNo = 0;

  // stage xT[t][b] once (sc so later cached reads are fresh)
  for (int i = bid*NTHR+tid; i < BB*TT; i += NBLK*NTHR) {
    int b = i>>9, t = i&(TT-1);
    __hip_atomic_store(&xT[t*BB+b], x[i], __ATOMIC_RELAXED, __HIP_MEMORY_SCOPE_AGENT);
  }

  for (int layer = 0; layer < 2; ++layer) {
    const float* Wgh_l = Wgh + (size_t)layer*HH*HH;
    const float* Wih_l = Wih + (size_t)layer*HH*HH;
    const float* Wfh_l = Wfh + (size_t)layer*HH*HH;
    const float* Woh_l = Woh + (size_t)layer*HH*HH;
    const float* Wgx_l = Wgx + (size_t)layer*VV*HH;
    const float* Wix_l = Wix + (size_t)layer*VV*HH;
    const float* Wfx_l = Wfx + (size_t)layer*VV*HH;
    const float* Wox_l = Wox + (size_t)layer*VV*HH;
    const float* Wph_l = Wph + (size_t)layer*HH*VV;
    const float* bg_l = bg + layer*HH, *bi_l = bi + layer*HH;
    const float* bf_l = bf_ + layer*HH, *bo_l = bo + layer*HH;
    const float* bp_l = bp + layer*VV;
    const int KCTOT = layer ? 40 : 32;   // kc count incl. L1's p0 K-extension

    // ---- stage gate-weight B-frags (hi/lo), once per layer ----
    for (int idx = tid; idx < KCTOT*64; idx += NTHR) {
      int kc = idx>>6, ln = idx&63;
      int col = ln&15, koct = ln>>4;
      int g = col>>2, hcl = col&3;
      const float* Wh = (g==0)?Wgh_l:(g==1)?Wih_l:(g==2)?Wfh_l:Woh_l;
      const float* Wx = (g==0)?Wgx_l:(g==1)?Wix_l:(g==2)?Wfx_l:Wox_l;
      #pragma unroll
      for (int j = 0; j < 8; ++j) {
        int k = kc*32 + koct*8 + j;
        float w = (k < HH) ? Wh[(size_t)k*HH + jb + hcl]
                           : Wx[(size_t)(k-HH)*HH + jb + hcl];
        unsigned short hi = bf16hi(w);
        wlds[((kc*2+0)*64+ln)*8+j] = hi;
        wlds[((kc*2+1)*64+ln)*8+j] = bf16hi(w - bf16dec(hi));
      }
    }
    // ---- stage wph B-frags for this block's p-slice ----
    for (int idx = tid; idx < 16*64; idx += NTHR) {
      int pbq = idx>>6, ln = idx&63;
      int pcol = p_cg*16 + (ln&15);
      #pragma unroll
      for (int j = 0; j < 8; ++j) {
        int k = p_kh*512 + pbq*32 + (ln>>4)*8 + j;
        float w = Wph_l[(size_t)k*VV + pcol];
        unsigned short hi = bf16hi(w);
        wplds[((pbq*2+0)*64+ln)*8+j] = hi;
        wplds[((pbq*2+1)*64+ln)*8+j] = bf16hi(w - bf16dec(hi));
      }
    }
    float c_reg = 0.f, own_prev = 0.f;
    gbar(flags, ++roundNo, tid, bid);

    for (int t = 0; t <= TT+1; ++t) {
      const char* hprev = (t&1) ? hFA : hFB;   // h[t-1]
      char*       hcur  = (t&1) ? hFB : hFA;   // h[t]
      const bool gates_on = (t < TT);
      const bool p_on     = (t >= 1 && t <= TT);
      const bool hrun     = gates_on && (t > 0);
      const bool ranz     = gates_on && (t > 0 || layer == 1);

      // ---- finalize p[t-2]: own(prev step) + partner partial + bias ----
      if (t >= 2 && p_kh == 0 && tid < 256) {
        float partner = __hip_atomic_load(&gpart[(size_t)((t-1)&1)*NBLK*256 + (size_t)(bid+128)*256 + tid],
                                          __ATOMIC_RELAXED, __HIP_MEMORY_SCOPE_AGENT);
        int row = tid>>4, col = tid&15;
        int pcol = p_cg*16 + col;
        float pv = own_prev + partner + bp_l[pcol];
        if (layer == 0) {  // p0 -> frag-packed bf16 hi/lo into d_out slice t-2
          unsigned short hi = bf16hi(pv);
          unsigned short lo = bf16hi(pv - bf16dec(hi));
          size_t off = (size_t)(t-2)*131072 + (size_t)p_s*16384 + (size_t)(pcol>>5)*2048
                     + (size_t)(row + 16*((pcol>>3)&3))*16 + (size_t)(pcol&7)*2;
          unsigned short* o = (unsigned short*)((char*)seq + off);
          st16(o, hi); st16(o + 512, lo);        // +512 shorts = lo plane (+1024 B)
        } else {           // p1 -> final fp32 output
          int b = p_s*16 + row;
          seq[(size_t)(t-2)*BB*VV + (size_t)b*VV + pcol] = pv;
        }
      }

      // ---- gate GEMM: h-part (kc 0..31) ----
      f32x4 acc = {0.f,0.f,0.f,0.f};
      if (hrun) {
        const char* ab = hprev + (size_t)wv*65536 + (size_t)lane*16;  // strip stride 32*2*1024
        for (int kc = 0; kc < 32; kc += 4) {
          i32x4 q0,q1,q2,q3,q4,q5,q6,q7;
          const char* a0 = ab + (size_t)kc*2048;
          SCLOAD(q0, a0);        SCLOAD(q1, a0+1024);
          SCLOAD(q2, a0+2048);   SCLOAD(q3, a0+3072);
          SCLOAD(q4, a0+4096);   SCLOAD(q5, a0+5120);
          SCLOAD(q6, a0+6144);   SCLOAD(q7, a0+7168);
          WAIT0_8(q0,q1,q2,q3,q4,q5,q6,q7);
          GBODY(q0,q1,kc); GBODY(q2,q3,kc+1); GBODY(q4,q5,kc+2); GBODY(q6,q7,kc+3);
        }
      }
      // ---- gate GEMM: L1 K-extension from p0F (kc 32..39) ----
      if (gates_on && layer == 1) {
        const char* eb = (const char*)seq + (size_t)t*131072 + (size_t)wv*16384 + (size_t)lane*16;
        for (int kc2 = 0; kc2 < 8; kc2 += 4) {
          i32x4 q0,q1,q2,q3,q4,q5,q6,q7;
          const char* a0 = eb + (size_t)kc2*2048;
          SCLOAD(q0, a0);        SCLOAD(q1, a0+1024);
          SCLOAD(q2, a0+2048);   SCLOAD(q3, a0+3072);
          SCLOAD(q4, a0+4096);   SCLOAD(q5, a0+5120);
          SCLOAD(q6, a0+6144);   SCLOAD(q7, a0+7168);
          WAIT0_8(q0,q1,q2,q3,q4,q5,q6,q7);
          GBODY(q0,q1,32+kc2); GBODY(q2,q3,33+kc2); GBODY(q4,q5,34+kc2); GBODY(q6,q7,35+kc2);
        }
      }

      // ---- p-slice partial (2 kc per wave, from h[t-1] at strip p_s) ----
      f32x4 pacc = {0.f,0.f,0.f,0.f};
      if (p_on) {
        const int kcp = p_kh*16 + wv*2;
        const int pbq = wv*2;
        const char* pb_ = hprev + (size_t)p_s*65536 + (size_t)kcp*2048 + (size_t)lane*16;
        s16x8 b0h = *(const s16x8*)&wplds[((pbq*2+0)*64+lane)*8];
        s16x8 b0l = *(const s16x8*)&wplds[((pbq*2+1)*64+lane)*8];
        s16x8 b1h = *(const s16x8*)&wplds[(((pbq+1)*2+0)*64+lane)*8];
        s16x8 b1l = *(const s16x8*)&wplds[(((pbq+1)*2+1)*64+lane)*8];
        i32x4 a0,a1,a2,a3;
        SCLOAD(a0, pb_);        SCLOAD(a1, pb_+1024);
        SCLOAD(a2, pb_+2048);   SCLOAD(a3, pb_+3072);
        WAIT0_4(a0,a1,a2,a3);
        s16x8 A0h = __builtin_bit_cast(s16x8, a0), A0l = __builtin_bit_cast(s16x8, a1);
        s16x8 A1h = __builtin_bit_cast(s16x8, a2), A1l = __builtin_bit_cast(s16x8, a3);
        pacc = __builtin_amdgcn_mfma_f32_16x16x32_bf16(A0h, b0h, pacc, 0,0,0);
        pacc = __builtin_amdgcn_mfma_f32_16x16x32_bf16(A0h, b0l, pacc, 0,0,0);
        pacc = __builtin_amdgcn_mfma_f32_16x16x32_bf16(A0l, b0h, pacc, 0,0,0);
        pacc = __builtin_amdgcn_mfma_f32_16x16x32_bf16(A1h, b1h, pacc, 0,0,0);
        pacc = __builtin_amdgcn_mfma_f32_16x16x32_bf16(A1h, b1l, pacc, 0,0,0);
        pacc = __builtin_amdgcn_mfma_f32_16x16x32_bf16(A1l, b1h, pacc, 0,0,0);
      }

      // ---- D-frag exchange (col = lane&15, row = (lane>>4)*4 + reg) ----
      if (ranz) {
        int q = lane>>4, c0 = lane&15;
        zex[(wv*16 + q*4 + 0)*16 + c0] = acc.x;
        zex[(wv*16 + q*4 + 1)*16 + c0] = acc.y;
        zex[(wv*16 + q*4 + 2)*16 + c0] = acc.z;
        zex[(wv*16 + q*4 + 3)*16 + c0] = acc.w;
      }
      if (p_on) {
        int q = lane>>4, c0 = lane&15;
        pex[wv*256 + (q*4 + 0)*16 + c0] = pacc.x;
        pex[wv*256 + (q*4 + 1)*16 + c0] = pacc.y;
        pex[wv*256 + (q*4 + 2)*16 + c0] = pacc.z;
        pex[wv*256 + (q*4 + 3)*16 + c0] = pacc.w;
      }
      __syncthreads();

      // ---- LSTM cell update ----
      if (gates_on) {
        float z0 = bg_l[jb+u_hc], z1 = bi_l[jb+u_hc], z2 = bf_l[jb+u_hc], z3 = bo_l[jb+u_hc];
        if (ranz) {
          z0 += zex[u_b*16 +  0 + u_hc];
          z1 += zex[u_b*16 +  4 + u_hc];
          z2 += zex[u_b*16 +  8 + u_hc];
          z3 += zex[u_b*16 + 12 + u_hc];
        }
        if (layer == 0) {   // one-hot x contribution: fp32 row gather
          int tok = xT[t*BB + u_b];
          z0 += Wgx_l[(size_t)tok*HH + jb + u_hc];
          z1 += Wix_l[(size_t)tok*HH + jb + u_hc];
          z2 += Wfx_l[(size_t)tok*HH + jb + u_hc];
          z3 += Wox_l[(size_t)tok*HH + jb + u_hc];
        }
        float G = tanhf(z0), I = sigf(z1), F = sigf(z2), O = sigf(z3);
        c_reg = fmaf(G, I, c_reg * F);
        float hv = tanhf(c_reg) * O;
        int k = jb + u_hc;
        size_t off = ((size_t)(u_b>>4)*32 + (size_t)(k>>5))*2048
                   + (size_t)((u_b&15) + 16*((k>>3)&3))*16 + (size_t)(k&7)*2;
        unsigned short* o = (unsigned short*)(hcur + off);
        unsigned short hh = bf16hi(hv);
        st16(o, hh); st16(o + 512, bf16hi(hv - bf16dec(hh)));
      }
      // ---- p partial block-sum + publish ----
      if (p_on && tid < 256) {
        float s = 0.f;
        #pragma unroll
        for (int wq = 0; wq < 8; ++wq) s += pex[wq*256 + tid];
        __hip_atomic_store(&gpart[(size_t)(t&1)*NBLK*256 + (size_t)bid*256 + tid], s,
                           __ATOMIC_RELAXED, __HIP_MEMORY_SCOPE_AGENT);
        own_prev = s;
      }
      gbar(flags, ++roundNo, tid, bid);
    }
  }
}

extern "C" void kernel_launch(void* const* d_in, const int* in_sizes, int n_in,
                              void* d_out, int out_size, void* d_ws, size_t ws_size,
                              hipStream_t stream)
{
  const int*   x   = (const int*)  d_in[0];
  const float* Wgx = (const float*)d_in[1];
  const float* Wgh = (const float*)d_in[2];
  const float* Wix = (const float*)d_in[3];
  const float* Wih = (const float*)d_in[4];
  const float* Wfx = (const float*)d_in[5];
  const float* Wfh = (const float*)d_in[6];
  const float* Wox = (const float*)d_in[7];
  const float* Woh = (const float*)d_in[8];
  const float* Wph = (const float*)d_in[9];
  const float* bg  = (const float*)d_in[10];
  const float* bi  = (const float*)d_in[11];
  const float* bf  = (const float*)d_in[12];
  const float* bo  = (const float*)d_in[13];
  const float* bp  = (const float*)d_in[14];

  float*    seq   = (float*)d_out;
  char*     base  = (char*)d_ws;
  unsigned* flags = (unsigned*)base;                 //   4 KB
  int*      xT    = (int*)(base + 4096);             // 256 KB
  char*     hFA   = base + 4096 + 262144;            // 512 KB
  char*     hFB   = hFA + 524288;                    // 512 KB
  float*    gpart = (float*)(hFB + 524288);          // 512 KB

  hipMemsetAsync(flags, 0, 4096, stream);

  void* args[] = { (void*)&x,
                   (void*)&Wgx, (void*)&Wgh, (void*)&Wix, (void*)&Wih,
                   (void*)&Wfx, (void*)&Wfh, (void*)&Wox, (void*)&Woh,
                   (void*)&Wph,
                   (void*)&bg, (void*)&bi, (void*)&bf, (void*)&bo, (void*)&bp,
                   (void*)&seq, (void*)&hFA, (void*)&hFB,
                   (void*)&gpart, (void*)&xT, (void*)&flags };

  hipLaunchCooperativeKernel((const void*)lstm_mfma, dim3(NBLK), dim3(NTHR),
                             args, 0, stream);
}